// Round 1
// baseline (456.201 us; speedup 1.0000x reference)
//
#include <hip/hip_runtime.h>
#include <hip/hip_bf16.h>

// B=2, T=2048, C=1024, H=16, D=64
// Pipeline: qkv_gemm (f32->bf16 MFMA) -> flash attn (bf16 MFMA) -> proj_gemm (f32 out)

typedef __attribute__((ext_vector_type(8))) short bf16x8;
typedef __attribute__((ext_vector_type(4))) short bf16x4;
typedef __attribute__((ext_vector_type(4))) float f32x4;

__device__ __forceinline__ short f2bs(float f) {
    union { __hip_bfloat16 h; short s; } u;
    u.h = __float2bfloat16(f);
    return u.s;
}

// ---------------------------------------------------------------------------
// Kernel 1: QKV GEMM.  X[4096][1024] f32 x W[1024][3072] f32 (+bias)
//   -> Q,K as bf16 [B*H][T][D], V as bf16 transposed [B*H][D][T]
// 128x128 block tile, BK=32, 4 waves (2x2), each wave 64x64 via 4x4 16x16 frags
// ---------------------------------------------------------------------------
__global__ __launch_bounds__(256) void qkv_gemm(
    const float* __restrict__ X, const float* __restrict__ W,
    const float* __restrict__ bias,
    short* __restrict__ Qw, short* __restrict__ Kw, short* __restrict__ Vt)
{
    __shared__ short Alds[128 * 40];   // [row m][k] pad to 40 (80B stride, 16B aligned)
    __shared__ short Blds[128 * 40];   // [col n][k] (B stored transposed)
    const int tid  = threadIdx.x;
    const int lane = tid & 63;
    const int wid  = tid >> 6;
    const int wm = wid >> 1, wn = wid & 1;
    const int g = lane >> 4, cc = lane & 15;
    const int m0 = blockIdx.y * 128, n0 = blockIdx.x * 128;

    f32x4 acc[4][4];
    const f32x4 zero4 = {0.f, 0.f, 0.f, 0.f};
    #pragma unroll
    for (int i = 0; i < 4; i++)
        #pragma unroll
        for (int j = 0; j < 4; j++) acc[i][j] = zero4;

    for (int k0 = 0; k0 < 1024; k0 += 32) {
        // stage A: 128x32 f32 -> bf16.  1024 float4 loads over 256 threads.
        #pragma unroll
        for (int i = 0; i < 4; i++) {
            int f = tid + 256 * i;
            int row = f >> 3, c4 = f & 7;
            float4 v = *(const float4*)(X + (size_t)(m0 + row) * 1024 + k0 + c4 * 4);
            bf16x4 s; s[0] = f2bs(v.x); s[1] = f2bs(v.y); s[2] = f2bs(v.z); s[3] = f2bs(v.w);
            *(bf16x4*)&Alds[row * 40 + c4 * 4] = s;
        }
        // stage B transposed: W[k][n] -> Blds[n][k]
        #pragma unroll
        for (int i = 0; i < 4; i++) {
            int f = tid + 256 * i;
            int r = f >> 5, c4 = f & 31;
            float4 v = *(const float4*)(W + (size_t)(k0 + r) * 3072 + n0 + c4 * 4);
            Blds[(c4 * 4 + 0) * 40 + r] = f2bs(v.x);
            Blds[(c4 * 4 + 1) * 40 + r] = f2bs(v.y);
            Blds[(c4 * 4 + 2) * 40 + r] = f2bs(v.z);
            Blds[(c4 * 4 + 3) * 40 + r] = f2bs(v.w);
        }
        __syncthreads();

        bf16x8 af[4], bfr[4];
        #pragma unroll
        for (int m = 0; m < 4; m++)
            af[m] = *(const bf16x8*)&Alds[(wm * 64 + m * 16 + cc) * 40 + g * 8];
        #pragma unroll
        for (int n = 0; n < 4; n++)
            bfr[n] = *(const bf16x8*)&Blds[(wn * 64 + n * 16 + cc) * 40 + g * 8];
        #pragma unroll
        for (int m = 0; m < 4; m++)
            #pragma unroll
            for (int n = 0; n < 4; n++)
                acc[m][n] = __builtin_amdgcn_mfma_f32_16x16x32_bf16(af[m], bfr[n], acc[m][n], 0, 0, 0);
        __syncthreads();
    }

    // epilogue: split q/k/v, heads; V written transposed [bh][d][t]
    #pragma unroll
    for (int n = 0; n < 4; n++) {
        int col = n0 + wn * 64 + n * 16 + cc;
        int which = col >> 10;
        int ci = col & 1023;
        int h = ci >> 6, d = ci & 63;
        float bv = bias[col];
        #pragma unroll
        for (int m = 0; m < 4; m++) {
            #pragma unroll
            for (int r = 0; r < 4; r++) {
                int row = m0 + wm * 64 + m * 16 + g * 4 + r;
                int b = row >> 11, t = row & 2047;
                int bh = b * 16 + h;
                short s = f2bs(acc[m][n][r] + bv);
                if (which == 0)      Qw[((size_t)bh * 2048 + t) * 64 + d] = s;
                else if (which == 1) Kw[((size_t)bh * 2048 + t) * 64 + d] = s;
                else                 Vt[((size_t)bh * 64 + d) * 2048 + t] = s;
            }
        }
    }
}

// ---------------------------------------------------------------------------
// Kernel 2: causal flash attention. 1 wave per 16 q-rows per (b,h).
// scores = (Q K^T)/sqrt(C); online softmax; O = P V.  K/V read from global
// (256KB/head -> L2-resident across the 128 q-blocks of a head).
// ---------------------------------------------------------------------------
__global__ __launch_bounds__(64) void attn_kernel(
    const short* __restrict__ Qw, const short* __restrict__ Kw,
    const short* __restrict__ Vt, short* __restrict__ Aout)
{
    __shared__ short Plds[16 * 40];
    const int lane = threadIdx.x;
    const int g = lane >> 4, cc = lane & 15;
    const int q0 = blockIdx.x * 16;
    const int bh = blockIdx.y;
    const int b = bh >> 4, h = bh & 15;
    const short* Qb = Qw + (size_t)bh * 2048 * 64;
    const short* Kb = Kw + (size_t)bh * 2048 * 64;
    const short* Vb = Vt + (size_t)bh * 64 * 2048;

    // Q fragments (A operand): row = lane&15, k = (lane>>4)*8+j (+32 per d-step)
    bf16x8 qf[2];
    #pragma unroll
    for (int ds = 0; ds < 2; ds++)
        qf[ds] = *(const bf16x8*)(Qb + (q0 + cc) * 64 + ds * 32 + g * 8);

    const f32x4 zero4 = {0.f, 0.f, 0.f, 0.f};
    f32x4 o[4];
    float m_r[4], l_r[4];
    #pragma unroll
    for (int i = 0; i < 4; i++) { o[i] = zero4; m_r[i] = -1e30f; l_r[i] = 0.f; }

    const float SC = 0.03125f * 1.44269504f;   // (1/sqrt(C)) * log2(e)
    const int nsteps = ((q0 + 15) >> 5) + 1;

    for (int st = 0; st < nsteps; st++) {
        const int kv0 = st * 32;
        // S = Q K^T for 32 kv cols (two 16x16 tiles)
        f32x4 s[2] = {zero4, zero4};
        #pragma unroll
        for (int kvc = 0; kvc < 2; kvc++) {
            #pragma unroll
            for (int ds = 0; ds < 2; ds++) {
                bf16x8 kf = *(const bf16x8*)(Kb + (kv0 + kvc * 16 + cc) * 64 + ds * 32 + g * 8);
                s[kvc] = __builtin_amdgcn_mfma_f32_16x16x32_bf16(qf[ds], kf, s[kvc], 0, 0, 0);
            }
        }
        // online softmax; C-layout: q-row = g*4+r, kv-col = cc (+16 for tile 1)
        float p0v[4], p1v[4], alpha[4];
        #pragma unroll
        for (int r = 0; r < 4; r++) {
            int qrow = q0 + g * 4 + r;
            float s0 = s[0][r] * SC, s1 = s[1][r] * SC;
            if (kv0 + cc      > qrow) s0 = -1e30f;
            if (kv0 + 16 + cc > qrow) s1 = -1e30f;
            float mx = fmaxf(s0, s1);
            mx = fmaxf(mx, __shfl_xor(mx, 1));
            mx = fmaxf(mx, __shfl_xor(mx, 2));
            mx = fmaxf(mx, __shfl_xor(mx, 4));
            mx = fmaxf(mx, __shfl_xor(mx, 8));
            float mn = fmaxf(m_r[r], mx);
            float a  = exp2f(m_r[r] - mn);
            float p0 = exp2f(s0 - mn), p1 = exp2f(s1 - mn);
            float rs = p0 + p1;
            rs += __shfl_xor(rs, 1);
            rs += __shfl_xor(rs, 2);
            rs += __shfl_xor(rs, 4);
            rs += __shfl_xor(rs, 8);
            l_r[r] = l_r[r] * a + rs;
            m_r[r] = mn;
            alpha[r] = a;
            p0v[r] = p0; p1v[r] = p1;
        }
        #pragma unroll
        for (int ch = 0; ch < 4; ch++)
            #pragma unroll
            for (int r = 0; r < 4; r++) o[ch][r] *= alpha[r];

        // transpose P (C-layout) -> A-fragment layout via LDS
        #pragma unroll
        for (int r = 0; r < 4; r++) {
            Plds[(g * 4 + r) * 40 + cc]      = f2bs(p0v[r]);
            Plds[(g * 4 + r) * 40 + 16 + cc] = f2bs(p1v[r]);
        }
        __syncthreads();
        bf16x8 pa = *(const bf16x8*)&Plds[cc * 40 + g * 8];
        #pragma unroll
        for (int ch = 0; ch < 4; ch++) {
            bf16x8 vf = *(const bf16x8*)(Vb + (ch * 16 + cc) * 2048 + kv0 + g * 8);
            o[ch] = __builtin_amdgcn_mfma_f32_16x16x32_bf16(pa, vf, o[ch], 0, 0, 0);
        }
        __syncthreads();
    }

    // write attention output as bf16 [B][T][C] (heads re-interleaved)
    #pragma unroll
    for (int ch = 0; ch < 4; ch++) {
        #pragma unroll
        for (int r = 0; r < 4; r++) {
            int t = q0 + g * 4 + r;
            float ov = o[ch][r] / l_r[r];
            Aout[((size_t)b * 2048 + t) * 1024 + h * 64 + ch * 16 + cc] = f2bs(ov);
        }
    }
}

// ---------------------------------------------------------------------------
// Kernel 3: output projection. A bf16 [4096][1024] x W_proj f32 [1024][1024]
//   -> f32 out [4096][1024] (+bias)
// ---------------------------------------------------------------------------
__global__ __launch_bounds__(256) void proj_gemm(
    const short* __restrict__ A, const float* __restrict__ W,
    const float* __restrict__ bias, float* __restrict__ Out)
{
    __shared__ short Alds[128 * 40];
    __shared__ short Blds[128 * 40];
    const int tid  = threadIdx.x;
    const int lane = tid & 63;
    const int wid  = tid >> 6;
    const int wm = wid >> 1, wn = wid & 1;
    const int g = lane >> 4, cc = lane & 15;
    const int m0 = blockIdx.y * 128, n0 = blockIdx.x * 128;

    f32x4 acc[4][4];
    const f32x4 zero4 = {0.f, 0.f, 0.f, 0.f};
    #pragma unroll
    for (int i = 0; i < 4; i++)
        #pragma unroll
        for (int j = 0; j < 4; j++) acc[i][j] = zero4;

    for (int k0 = 0; k0 < 1024; k0 += 32) {
        // stage A (already bf16): 512 x 16B loads over 256 threads
        #pragma unroll
        for (int i = 0; i < 2; i++) {
            int f = tid + 256 * i;
            int row = f >> 2, c8 = f & 3;
            bf16x8 v = *(const bf16x8*)(A + (size_t)(m0 + row) * 1024 + k0 + c8 * 8);
            *(bf16x8*)&Alds[row * 40 + c8 * 8] = v;
        }
        // stage B transposed f32->bf16
        #pragma unroll
        for (int i = 0; i < 4; i++) {
            int f = tid + 256 * i;
            int r = f >> 5, c4 = f & 31;
            float4 v = *(const float4*)(W + (size_t)(k0 + r) * 1024 + n0 + c4 * 4);
            Blds[(c4 * 4 + 0) * 40 + r] = f2bs(v.x);
            Blds[(c4 * 4 + 1) * 40 + r] = f2bs(v.y);
            Blds[(c4 * 4 + 2) * 40 + r] = f2bs(v.z);
            Blds[(c4 * 4 + 3) * 40 + r] = f2bs(v.w);
        }
        __syncthreads();

        bf16x8 af[4], bfr[4];
        #pragma unroll
        for (int m = 0; m < 4; m++)
            af[m] = *(const bf16x8*)&Alds[(wm * 64 + m * 16 + cc) * 40 + g * 8];
        #pragma unroll
        for (int n = 0; n < 4; n++)
            bfr[n] = *(const bf16x8*)&Blds[(wn * 64 + n * 16 + cc) * 40 + g * 8];
        #pragma unroll
        for (int m = 0; m < 4; m++)
            #pragma unroll
            for (int n = 0; n < 4; n++)
                acc[m][n] = __builtin_amdgcn_mfma_f32_16x16x32_bf16(af[m], bfr[n], acc[m][n], 0, 0, 0);
        __syncthreads();
    }

    #pragma unroll
    for (int n = 0; n < 4; n++) {
        int col = n0 + wn * 64 + n * 16 + cc;
        float bv = bias[col];
        #pragma unroll
        for (int m = 0; m < 4; m++) {
            #pragma unroll
            for (int r = 0; r < 4; r++) {
                int row = m0 + wm * 64 + m * 16 + g * 4 + r;
                Out[(size_t)row * 1024 + col] = acc[m][n][r] + bv;
            }
        }
    }
}

// ---------------------------------------------------------------------------
extern "C" void kernel_launch(void* const* d_in, const int* in_sizes, int n_in,
                              void* d_out, int out_size, void* d_ws, size_t ws_size,
                              hipStream_t stream)
{
    const float* x      = (const float*)d_in[0];
    const float* W_attn = (const float*)d_in[1];
    const float* b_attn = (const float*)d_in[2];
    const float* W_proj = (const float*)d_in[3];
    const float* b_proj = (const float*)d_in[4];
    float* out = (float*)d_out;

    const size_t SZ = (size_t)4096 * 1024;   // B*T * C elements
    short* Qw   = (short*)d_ws;              // [B*H][T][D] bf16
    short* Kw   = Qw + SZ;                   // [B*H][T][D] bf16
    short* Vt   = Kw + SZ;                   // [B*H][D][T] bf16
    short* Aout = Vt + SZ;                   // [B][T][C]   bf16

    qkv_gemm<<<dim3(24, 32), 256, 0, stream>>>(x, W_attn, b_attn, Qw, Kw, Vt);
    attn_kernel<<<dim3(128, 32), 64, 0, stream>>>(Qw, Kw, Vt, Aout);
    proj_gemm<<<dim3(8, 32), 256, 0, stream>>>(Aout, W_proj, b_proj, out);
}

// Round 2
// 266.008 us; speedup vs baseline: 1.7150x; 1.7150x over previous
//
#include <hip/hip_runtime.h>
#include <hip/hip_bf16.h>

// B=2, T=2048, C=1024, H=16, D=64
// convt(W_attn) -> qkv_gemm -> attn_v3 -> convt(W_proj) -> proj_gemm

typedef __attribute__((ext_vector_type(8))) short bf16x8;
typedef __attribute__((ext_vector_type(4))) short bf16x4;
typedef __attribute__((ext_vector_type(4))) float f32x4;

__device__ __forceinline__ short f2bs(float f) {
    union { __hip_bfloat16 h; short s; } u;
    u.h = __float2bfloat16(f);
    return u.s;
}

#define GLOAD_LDS16(gp, lp)                                                        \
    __builtin_amdgcn_global_load_lds((const __attribute__((address_space(1))) void*)(gp), \
                                     (__attribute__((address_space(3))) void*)(lp), 16, 0, 0)

// ---------------------------------------------------------------------------
// convert + transpose: W f32 [K][N] -> Wt bf16 [N][K].  64x64 tiles via LDS.
// ---------------------------------------------------------------------------
__global__ __launch_bounds__(256) void convt(
    const float* __restrict__ W, short* __restrict__ Wt, int K, int N)
{
    __shared__ short t[64 * 72];
    const int tid = threadIdx.x;
    const int n0 = blockIdx.x * 64, k0 = blockIdx.y * 64;
    #pragma unroll
    for (int i = 0; i < 4; i++) {
        int k = (tid >> 4) + i * 16;
        int n = (tid & 15) * 4;
        float4 v = *(const float4*)(W + (size_t)(k0 + k) * N + n0 + n);
        t[(n + 0) * 72 + k] = f2bs(v.x);
        t[(n + 1) * 72 + k] = f2bs(v.y);
        t[(n + 2) * 72 + k] = f2bs(v.z);
        t[(n + 3) * 72 + k] = f2bs(v.w);
    }
    __syncthreads();
    #pragma unroll
    for (int i = 0; i < 2; i++) {
        int n  = (tid >> 3) + i * 32;
        int kc = (tid & 7) * 8;
        bf16x8 v = *(const bf16x8*)&t[n * 72 + kc];
        *(bf16x8*)(Wt + (size_t)(n0 + n) * K + k0 + kc) = v;
    }
}

// ---------------------------------------------------------------------------
// Kernel 1: QKV GEMM.  X f32 [4096][1024] x Wt bf16 [3072][1024] (+bias)
// 128x128 tile, BK=64, 4 waves (2x2). A staged f32->bf16, B via global_load_lds.
// ---------------------------------------------------------------------------
__global__ __launch_bounds__(256) void qkv_gemm(
    const float* __restrict__ X, const short* __restrict__ Wt,
    const float* __restrict__ bias,
    short* __restrict__ Qw, short* __restrict__ Kw, short* __restrict__ Vt)
{
    __shared__ short Al[128 * 64];
    __shared__ short Bl[128 * 64];
    const int tid  = threadIdx.x;
    const int lane = tid & 63;
    const int wid  = tid >> 6;
    const int wm = wid >> 1, wn = wid & 1;
    const int g = lane >> 4, cc = lane & 15;
    const int m0 = blockIdx.y * 128, n0 = blockIdx.x * 128;

    f32x4 acc[4][4];
    const f32x4 z4 = {0.f, 0.f, 0.f, 0.f};
    #pragma unroll
    for (int i = 0; i < 4; i++)
        #pragma unroll
        for (int j = 0; j < 4; j++) acc[i][j] = z4;

    const int arow = tid >> 1, ahalf = tid & 1;

    for (int k0 = 0; k0 < 1024; k0 += 64) {
        // A stage: 128x64 f32 -> bf16 (each thread: 1 row x 32 cols)
        {
            const float* src = X + (size_t)(m0 + arow) * 1024 + k0 + ahalf * 32;
            short* dst = &Al[arow * 64 + ahalf * 32];
            #pragma unroll
            for (int j = 0; j < 4; j++) {
                float4 a = *(const float4*)(src + j * 8);
                float4 b = *(const float4*)(src + j * 8 + 4);
                bf16x8 s;
                s[0] = f2bs(a.x); s[1] = f2bs(a.y); s[2] = f2bs(a.z); s[3] = f2bs(a.w);
                s[4] = f2bs(b.x); s[5] = f2bs(b.y); s[6] = f2bs(b.z); s[7] = f2bs(b.w);
                *(bf16x8*)(dst + j * 8) = s;
            }
        }
        // B stage: 128x64 bf16 via global_load_lds (16B/lane, 4 issues/thread)
        #pragma unroll
        for (int i = 0; i < 4; i++) {
            int chunk = (wid * 4 + i) * 64 + lane;
            int row = chunk >> 3, c = chunk & 7;
            const short* gp = Wt + (size_t)(n0 + row) * 1024 + k0 + c * 8;
            GLOAD_LDS16(gp, &Bl[chunk * 8]);
        }
        __syncthreads();

        #pragma unroll
        for (int kk = 0; kk < 2; kk++) {
            bf16x8 af[4], bfv[4];
            #pragma unroll
            for (int m = 0; m < 4; m++)
                af[m] = *(const bf16x8*)&Al[(wm * 64 + m * 16 + cc) * 64 + kk * 32 + g * 8];
            #pragma unroll
            for (int n = 0; n < 4; n++)
                bfv[n] = *(const bf16x8*)&Bl[(wn * 64 + n * 16 + cc) * 64 + kk * 32 + g * 8];
            #pragma unroll
            for (int m = 0; m < 4; m++)
                #pragma unroll
                for (int n = 0; n < 4; n++)
                    acc[m][n] = __builtin_amdgcn_mfma_f32_16x16x32_bf16(af[m], bfv[n], acc[m][n], 0, 0, 0);
        }
        __syncthreads();
    }

    // epilogue: split q/k/v + heads; V transposed [bh][d][t]
    #pragma unroll
    for (int n = 0; n < 4; n++) {
        int col = n0 + wn * 64 + n * 16 + cc;
        int which = col >> 10;
        int ci = col & 1023;
        int h = ci >> 6, d = ci & 63;
        float bv = bias[col];
        #pragma unroll
        for (int m = 0; m < 4; m++) {
            #pragma unroll
            for (int r = 0; r < 4; r++) {
                int row = m0 + wm * 64 + m * 16 + g * 4 + r;
                int b = row >> 11, t = row & 2047;
                int bh = b * 16 + h;
                short s = f2bs(acc[m][n][r] + bv);
                if (which == 0)      Qw[((size_t)bh * 2048 + t) * 64 + d] = s;
                else if (which == 1) Kw[((size_t)bh * 2048 + t) * 64 + d] = s;
                else                 Vt[((size_t)bh * 64 + d) * 2048 + t] = s;
            }
        }
    }
}

// ---------------------------------------------------------------------------
// Kernel 2: causal flash attention, swapped-operand S^T form.
// 1 wave / 16 q-rows. S^T = mfma(K,Q) -> per-lane softmax (2 shuffles) ->
// P via tiny LDS -> O^T = mfma(V^T, P^T).  No barriers; K prefetched.
// ---------------------------------------------------------------------------
__global__ __launch_bounds__(64) void attn_v3(
    const short* __restrict__ Qw, const short* __restrict__ Kw,
    const short* __restrict__ Vt, short* __restrict__ Aout)
{
    __shared__ short P[16 * 40];
    const int lane = threadIdx.x;
    const int g = lane >> 4, cc = lane & 15;
    const int bid = blockIdx.x;
    const int qt = 127 - (bid >> 5);     // longest q-tiles dispatched first
    const int bh = bid & 31;
    const int q0 = qt * 16;
    const int b = bh >> 4, h = bh & 15;
    const short* Qb = Qw + (size_t)bh * 2048 * 64;
    const short* Kb = Kw + (size_t)bh * 2048 * 64;
    const short* Vb = Vt + (size_t)bh * 64 * 2048;

    // Q as B-operand: lane holds col=q=cc, k=d=g*8..+7 (+32 for second half)
    bf16x8 qf0 = *(const bf16x8*)(Qb + (q0 + cc) * 64 + g * 8);
    bf16x8 qf1 = *(const bf16x8*)(Qb + (q0 + cc) * 64 + 32 + g * 8);

    f32x4 o[4];
    const f32x4 z4 = {0.f, 0.f, 0.f, 0.f};
    #pragma unroll
    for (int ch = 0; ch < 4; ch++) o[ch] = z4;
    float m_r = -1e30f, l_r = 0.f;
    const float SC = 0.04508422976f;     // log2(e)/sqrt(1024)
    const int nsteps = ((q0 + 15) >> 5) + 1;

    bf16x8 kf[4];                        // [kvc*2+ds]
    #pragma unroll
    for (int kvc = 0; kvc < 2; kvc++)
        #pragma unroll
        for (int ds = 0; ds < 2; ds++)
            kf[kvc * 2 + ds] = *(const bf16x8*)(Kb + (kvc * 16 + cc) * 64 + ds * 32 + g * 8);

    for (int st = 0; st < nsteps; st++) {
        const int kv0 = st * 32;
        const int kvn = (st + 1 < nsteps) ? kv0 + 32 : kv0;
        bf16x8 kn[4];
        #pragma unroll
        for (int kvc = 0; kvc < 2; kvc++)
            #pragma unroll
            for (int ds = 0; ds < 2; ds++)
                kn[kvc * 2 + ds] = *(const bf16x8*)(Kb + (kvn + kvc * 16 + cc) * 64 + ds * 32 + g * 8);

        // S^T tiles: rows=kv (g*4+r), cols=q (cc)
        f32x4 s0 = z4, s1 = z4;
        s0 = __builtin_amdgcn_mfma_f32_16x16x32_bf16(kf[0], qf0, s0, 0, 0, 0);
        s0 = __builtin_amdgcn_mfma_f32_16x16x32_bf16(kf[1], qf1, s0, 0, 0, 0);
        s1 = __builtin_amdgcn_mfma_f32_16x16x32_bf16(kf[2], qf0, s1, 0, 0, 0);
        s1 = __builtin_amdgcn_mfma_f32_16x16x32_bf16(kf[3], qf1, s1, 0, 0, 0);

        float sv[8];
        float mx = -1e30f;
        #pragma unroll
        for (int r = 0; r < 4; r++) {
            int kv = kv0 + g * 4 + r;
            float v0 = (kv      <= q0 + cc) ? s0[r] * SC : -1e30f;
            float v1 = (kv + 16 <= q0 + cc) ? s1[r] * SC : -1e30f;
            sv[r] = v0; sv[4 + r] = v1;
            mx = fmaxf(mx, fmaxf(v0, v1));
        }
        mx = fmaxf(mx, __shfl_xor(mx, 16));
        mx = fmaxf(mx, __shfl_xor(mx, 32));
        float mn = fmaxf(m_r, mx);
        float a = exp2f(m_r - mn);
        float p[8];
        float rs = 0.f;
        #pragma unroll
        for (int i = 0; i < 8; i++) { p[i] = exp2f(sv[i] - mn); rs += p[i]; }
        rs += __shfl_xor(rs, 16);
        rs += __shfl_xor(rs, 32);
        l_r = l_r * a + rs;
        m_r = mn;
        #pragma unroll
        for (int ch = 0; ch < 4; ch++)
            #pragma unroll
            for (int r = 0; r < 4; r++) o[ch][r] *= a;

        // P[q][kv] in LDS (row stride 40 shorts, 16B-aligned b128 reads)
        bf16x4 q4;
        q4[0] = f2bs(p[0]); q4[1] = f2bs(p[1]); q4[2] = f2bs(p[2]); q4[3] = f2bs(p[3]);
        *(bf16x4*)&P[cc * 40 + g * 4] = q4;
        q4[0] = f2bs(p[4]); q4[1] = f2bs(p[5]); q4[2] = f2bs(p[6]); q4[3] = f2bs(p[7]);
        *(bf16x4*)&P[cc * 40 + 16 + g * 4] = q4;
        asm volatile("s_waitcnt lgkmcnt(0)" ::: "memory");
        bf16x8 pa = *(const bf16x8*)&P[cc * 40 + g * 8];   // B-frag: col=q=cc, k=kv

        // O^T += V^T * P^T  (A = V^T rows d, k=kv)
        #pragma unroll
        for (int ch = 0; ch < 4; ch++) {
            bf16x8 vf = *(const bf16x8*)(Vb + (ch * 16 + cc) * 2048 + kv0 + g * 8);
            o[ch] = __builtin_amdgcn_mfma_f32_16x16x32_bf16(vf, pa, o[ch], 0, 0, 0);
        }
        #pragma unroll
        for (int i = 0; i < 4; i++) kf[i] = kn[i];
    }

    // O^T: col=q=cc -> t; rows d = ch*16 + g*4 + r
    float rl = 1.0f / l_r;
    const int t = q0 + cc;
    #pragma unroll
    for (int ch = 0; ch < 4; ch++) {
        bf16x4 ov;
        #pragma unroll
        for (int r = 0; r < 4; r++) ov[r] = f2bs(o[ch][r] * rl);
        *(bf16x4*)(Aout + ((size_t)b * 2048 + t) * 1024 + h * 64 + ch * 16 + g * 4) = ov;
    }
}

// ---------------------------------------------------------------------------
// Kernel 3: projection. A bf16 [4096][1024] x Wt bf16 [1024][1024] -> f32 +bias
// Both operands via global_load_lds.
// ---------------------------------------------------------------------------
__global__ __launch_bounds__(256) void proj_gemm(
    const short* __restrict__ A, const short* __restrict__ Wt,
    const float* __restrict__ bias, float* __restrict__ Out)
{
    __shared__ short Al[128 * 64];
    __shared__ short Bl[128 * 64];
    const int tid  = threadIdx.x;
    const int lane = tid & 63;
    const int wid  = tid >> 6;
    const int wm = wid >> 1, wn = wid & 1;
    const int g = lane >> 4, cc = lane & 15;
    const int m0 = blockIdx.y * 128, n0 = blockIdx.x * 128;

    f32x4 acc[4][4];
    const f32x4 z4 = {0.f, 0.f, 0.f, 0.f};
    #pragma unroll
    for (int i = 0; i < 4; i++)
        #pragma unroll
        for (int j = 0; j < 4; j++) acc[i][j] = z4;

    for (int k0 = 0; k0 < 1024; k0 += 64) {
        #pragma unroll
        for (int i = 0; i < 4; i++) {
            int chunk = (wid * 4 + i) * 64 + lane;
            int row = chunk >> 3, c = chunk & 7;
            GLOAD_LDS16(A + (size_t)(m0 + row) * 1024 + k0 + c * 8, &Al[chunk * 8]);
        }
        #pragma unroll
        for (int i = 0; i < 4; i++) {
            int chunk = (wid * 4 + i) * 64 + lane;
            int row = chunk >> 3, c = chunk & 7;
            GLOAD_LDS16(Wt + (size_t)(n0 + row) * 1024 + k0 + c * 8, &Bl[chunk * 8]);
        }
        __syncthreads();

        #pragma unroll
        for (int kk = 0; kk < 2; kk++) {
            bf16x8 af[4], bfv[4];
            #pragma unroll
            for (int m = 0; m < 4; m++)
                af[m] = *(const bf16x8*)&Al[(wm * 64 + m * 16 + cc) * 64 + kk * 32 + g * 8];
            #pragma unroll
            for (int n = 0; n < 4; n++)
                bfv[n] = *(const bf16x8*)&Bl[(wn * 64 + n * 16 + cc) * 64 + kk * 32 + g * 8];
            #pragma unroll
            for (int m = 0; m < 4; m++)
                #pragma unroll
                for (int n = 0; n < 4; n++)
                    acc[m][n] = __builtin_amdgcn_mfma_f32_16x16x32_bf16(af[m], bfv[n], acc[m][n], 0, 0, 0);
        }
        __syncthreads();
    }

    #pragma unroll
    for (int n = 0; n < 4; n++) {
        int col = n0 + wn * 64 + n * 16 + cc;
        float bv = bias[col];
        #pragma unroll
        for (int m = 0; m < 4; m++) {
            #pragma unroll
            for (int r = 0; r < 4; r++) {
                int row = m0 + wm * 64 + m * 16 + g * 4 + r;
                Out[(size_t)row * 1024 + col] = acc[m][n][r] + bv;
            }
        }
    }
}

// ---------------------------------------------------------------------------
extern "C" void kernel_launch(void* const* d_in, const int* in_sizes, int n_in,
                              void* d_out, int out_size, void* d_ws, size_t ws_size,
                              hipStream_t stream)
{
    const float* x      = (const float*)d_in[0];
    const float* W_attn = (const float*)d_in[1];
    const float* b_attn = (const float*)d_in[2];
    const float* W_proj = (const float*)d_in[3];
    const float* b_proj = (const float*)d_in[4];
    float* out = (float*)d_out;

    const size_t SZ = (size_t)4096 * 1024;     // 4M shorts per region
    short* R1 = (short*)d_ws;                  // Wt_attn (3072x1024), later Aout (4096x1024)
    short* Qw = R1 + SZ;                       // [B*H][T][D]; later Wt_proj (1024x1024)
    short* Kw = Qw + SZ;
    short* Vt = Kw + SZ;                       // [B*H][D][T]

    short* Wt_attn = R1;
    short* Aout    = R1;
    short* Wt_proj = Qw;

    convt<<<dim3(48, 16), 256, 0, stream>>>(W_attn, Wt_attn, 1024, 3072);
    qkv_gemm<<<dim3(24, 32), 256, 0, stream>>>(x, Wt_attn, b_attn, Qw, Kw, Vt);
    attn_v3<<<dim3(4096), 64, 0, stream>>>(Qw, Kw, Vt, Aout);
    convt<<<dim3(16, 16), 256, 0, stream>>>(W_proj, Wt_proj, 1024, 1024);
    proj_gemm<<<dim3(8, 32), 256, 0, stream>>>(Aout, Wt_proj, b_proj, out);
}

// Round 3
// 209.947 us; speedup vs baseline: 2.1729x; 1.2670x over previous
//
#include <hip/hip_runtime.h>
#include <hip/hip_bf16.h>

// B=2, T=2048, C=1024, H=16, D=64
// convt(W_attn) -> qkv_gemm (Q pre-scaled) -> attn_v4 -> convt(W_proj) -> proj_gemm

typedef __attribute__((ext_vector_type(8))) short bf16x8;
typedef __attribute__((ext_vector_type(4))) short bf16x4;
typedef __attribute__((ext_vector_type(4))) float f32x4;

__device__ __forceinline__ short f2bs(float f) {
    union { __hip_bfloat16 h; short s; } u;
    u.h = __float2bfloat16(f);
    return u.s;
}

#define GLOAD_LDS16(gp, lp)                                                        \
    __builtin_amdgcn_global_load_lds((const __attribute__((address_space(1))) void*)(gp), \
                                     (__attribute__((address_space(3))) void*)(lp), 16, 0, 0)

// ---------------------------------------------------------------------------
// convert + transpose: W f32 [K][N] -> Wt bf16 [N][K].  64x64 tiles via LDS.
// ---------------------------------------------------------------------------
__global__ __launch_bounds__(256) void convt(
    const float* __restrict__ W, short* __restrict__ Wt, int K, int N)
{
    __shared__ short t[64 * 72];
    const int tid = threadIdx.x;
    const int n0 = blockIdx.x * 64, k0 = blockIdx.y * 64;
    #pragma unroll
    for (int i = 0; i < 4; i++) {
        int k = (tid >> 4) + i * 16;
        int n = (tid & 15) * 4;
        float4 v = *(const float4*)(W + (size_t)(k0 + k) * N + n0 + n);
        t[(n + 0) * 72 + k] = f2bs(v.x);
        t[(n + 1) * 72 + k] = f2bs(v.y);
        t[(n + 2) * 72 + k] = f2bs(v.z);
        t[(n + 3) * 72 + k] = f2bs(v.w);
    }
    __syncthreads();
    #pragma unroll
    for (int i = 0; i < 2; i++) {
        int n  = (tid >> 3) + i * 32;
        int kc = (tid & 7) * 8;
        bf16x8 v = *(const bf16x8*)&t[n * 72 + kc];
        *(bf16x8*)(Wt + (size_t)(n0 + n) * K + k0 + kc) = v;
    }
}

// ---------------------------------------------------------------------------
// Kernel 1: QKV GEMM.  X f32 [4096][1024] x Wt bf16 [3072][1024] (+bias)
// 128x128 tile, BK=64, 4 waves. Al padded to stride 72 (bank-conflict fix).
// Q output pre-scaled by log2(e)/sqrt(C).
// ---------------------------------------------------------------------------
__global__ __launch_bounds__(256) void qkv_gemm(
    const float* __restrict__ X, const short* __restrict__ Wt,
    const float* __restrict__ bias,
    short* __restrict__ Qw, short* __restrict__ Kw, short* __restrict__ Vt)
{
    __shared__ short Al[128 * 72];
    __shared__ short Bl[128 * 64];
    const int tid  = threadIdx.x;
    const int lane = tid & 63;
    const int wid  = tid >> 6;
    const int wm = wid >> 1, wn = wid & 1;
    const int g = lane >> 4, cc = lane & 15;
    const int m0 = blockIdx.y * 128, n0 = blockIdx.x * 128;

    f32x4 acc[4][4];
    const f32x4 z4 = {0.f, 0.f, 0.f, 0.f};
    #pragma unroll
    for (int i = 0; i < 4; i++)
        #pragma unroll
        for (int j = 0; j < 4; j++) acc[i][j] = z4;

    const int arow = tid >> 1, ahalf = tid & 1;

    for (int k0 = 0; k0 < 1024; k0 += 64) {
        {
            const float* src = X + (size_t)(m0 + arow) * 1024 + k0 + ahalf * 32;
            short* dst = &Al[arow * 72 + ahalf * 32];
            #pragma unroll
            for (int j = 0; j < 4; j++) {
                float4 a = *(const float4*)(src + j * 8);
                float4 b = *(const float4*)(src + j * 8 + 4);
                bf16x8 s;
                s[0] = f2bs(a.x); s[1] = f2bs(a.y); s[2] = f2bs(a.z); s[3] = f2bs(a.w);
                s[4] = f2bs(b.x); s[5] = f2bs(b.y); s[6] = f2bs(b.z); s[7] = f2bs(b.w);
                *(bf16x8*)(dst + j * 8) = s;
            }
        }
        #pragma unroll
        for (int i = 0; i < 4; i++) {
            int chunk = (wid * 4 + i) * 64 + lane;
            int row = chunk >> 3, c = chunk & 7;
            GLOAD_LDS16(Wt + (size_t)(n0 + row) * 1024 + k0 + c * 8, &Bl[chunk * 8]);
        }
        __syncthreads();

        #pragma unroll
        for (int kk = 0; kk < 2; kk++) {
            bf16x8 af[4], bfv[4];
            #pragma unroll
            for (int m = 0; m < 4; m++)
                af[m] = *(const bf16x8*)&Al[(wm * 64 + m * 16 + cc) * 72 + kk * 32 + g * 8];
            #pragma unroll
            for (int n = 0; n < 4; n++)
                bfv[n] = *(const bf16x8*)&Bl[(wn * 64 + n * 16 + cc) * 64 + kk * 32 + g * 8];
            #pragma unroll
            for (int m = 0; m < 4; m++)
                #pragma unroll
                for (int n = 0; n < 4; n++)
                    acc[m][n] = __builtin_amdgcn_mfma_f32_16x16x32_bf16(af[m], bfv[n], acc[m][n], 0, 0, 0);
        }
        __syncthreads();
    }

    const float QSCALE = 0.04508422976f;   // log2(e)/sqrt(1024)
    #pragma unroll
    for (int n = 0; n < 4; n++) {
        int col = n0 + wn * 64 + n * 16 + cc;
        int which = col >> 10;
        int ci = col & 1023;
        int h = ci >> 6, d = ci & 63;
        float bv = bias[col];
        #pragma unroll
        for (int m = 0; m < 4; m++) {
            #pragma unroll
            for (int r = 0; r < 4; r++) {
                int row = m0 + wm * 64 + m * 16 + g * 4 + r;
                int b = row >> 11, t = row & 2047;
                int bh = b * 16 + h;
                float v = acc[m][n][r] + bv;
                if (which == 0)      Qw[((size_t)bh * 2048 + t) * 64 + d] = f2bs(v * QSCALE);
                else if (which == 1) Kw[((size_t)bh * 2048 + t) * 64 + d] = f2bs(v);
                else                 Vt[((size_t)bh * 64 + d) * 2048 + t] = f2bs(v);
            }
        }
    }
}

// ---------------------------------------------------------------------------
// Kernel 2: causal flash attention, swapped S^T form, 32 q-rows per wave.
// S^T = mfma(K, Q) (Q pre-scaled to log2 domain); per-lane softmax (2 shfl);
// defer-max rescale; P via LDS; O^T = mfma(V^T, P^T). K & V prefetched.
// ---------------------------------------------------------------------------
__global__ __launch_bounds__(64) void attn_v4(
    const short* __restrict__ Qw, const short* __restrict__ Kw,
    const short* __restrict__ Vt, short* __restrict__ Aout)
{
    __shared__ short P[2 * 16 * 40];
    const int lane = threadIdx.x;
    const int g = lane >> 4, cc = lane & 15;
    const int bid = blockIdx.x;
    const int qt = 63 - (bid >> 5);       // longest tiles first
    const int bh = bid & 31;              // XCD = bh % 8 -> per-head L2 locality
    const int q0 = qt * 32;
    const int b = bh >> 4, h = bh & 15;
    const short* Qb = Qw + (size_t)bh * 2048 * 64;
    const short* Kb = Kw + (size_t)bh * 2048 * 64;
    const short* Vb = Vt + (size_t)bh * 64 * 2048;

    // Q as B-operand: col = q0+qf*16+cc, k = d = ds*32 + g*8 + j
    bf16x8 qfr[2][2];
    #pragma unroll
    for (int qf = 0; qf < 2; qf++)
        #pragma unroll
        for (int ds = 0; ds < 2; ds++)
            qfr[qf][ds] = *(const bf16x8*)(Qb + (q0 + qf * 16 + cc) * 64 + ds * 32 + g * 8);

    const f32x4 z4 = {0.f, 0.f, 0.f, 0.f};
    f32x4 o[2][4];
    #pragma unroll
    for (int qf = 0; qf < 2; qf++)
        #pragma unroll
        for (int ch = 0; ch < 4; ch++) o[qf][ch] = z4;
    float m_r[2] = {-1e30f, -1e30f}, l_r[2] = {0.f, 0.f};

    const int nsteps = qt + 1;            // kv tiles 0..qt; only st==qt is masked

    bf16x8 kf[4], vf[4];                  // kf[kvc*2+ds]; vf[ch]
    #pragma unroll
    for (int kvc = 0; kvc < 2; kvc++)
        #pragma unroll
        for (int ds = 0; ds < 2; ds++)
            kf[kvc * 2 + ds] = *(const bf16x8*)(Kb + (kvc * 16 + cc) * 64 + ds * 32 + g * 8);
    #pragma unroll
    for (int ch = 0; ch < 4; ch++)
        vf[ch] = *(const bf16x8*)(Vb + (ch * 16 + cc) * 2048 + g * 8);

    for (int st = 0; st < nsteps; st++) {
        const int kv0 = st * 32;
        const int kvn = (st + 1 < nsteps) ? kv0 + 32 : kv0;
        bf16x8 kn[4], vn[4];
        #pragma unroll
        for (int kvc = 0; kvc < 2; kvc++)
            #pragma unroll
            for (int ds = 0; ds < 2; ds++)
                kn[kvc * 2 + ds] = *(const bf16x8*)(Kb + (kvn + kvc * 16 + cc) * 64 + ds * 32 + g * 8);
        #pragma unroll
        for (int ch = 0; ch < 4; ch++)
            vn[ch] = *(const bf16x8*)(Vb + (ch * 16 + cc) * 2048 + kvn + g * 8);

        // S^T tiles [qf][kvc]: rows kv = g*4+r, cols q = cc
        f32x4 s[2][2];
        #pragma unroll
        for (int qf = 0; qf < 2; qf++)
            #pragma unroll
            for (int kvc = 0; kvc < 2; kvc++) {
                s[qf][kvc] = z4;
                #pragma unroll
                for (int ds = 0; ds < 2; ds++)
                    s[qf][kvc] = __builtin_amdgcn_mfma_f32_16x16x32_bf16(
                        kf[kvc * 2 + ds], qfr[qf][ds], s[qf][kvc], 0, 0, 0);
            }

        const bool masked = (st == qt);
        #pragma unroll
        for (int qf = 0; qf < 2; qf++) {
            const int qq = q0 + qf * 16 + cc;
            float sv[8];
            #pragma unroll
            for (int kvc = 0; kvc < 2; kvc++)
                #pragma unroll
                for (int r = 0; r < 4; r++) {
                    float v = s[qf][kvc][r];
                    if (masked) {
                        int kv = kv0 + kvc * 16 + g * 4 + r;
                        v = (kv <= qq) ? v : -1e30f;
                    }
                    sv[kvc * 4 + r] = v;
                }
            float mx = fmaxf(fmaxf(fmaxf(sv[0], sv[1]), fmaxf(sv[2], sv[3])),
                             fmaxf(fmaxf(sv[4], sv[5]), fmaxf(sv[6], sv[7])));
            mx = fmaxf(mx, __shfl_xor(mx, 16));
            mx = fmaxf(mx, __shfl_xor(mx, 32));
            if (__any(mx > m_r[qf] + 6.0f)) {       // defer-max: rarely taken
                float mn = fmaxf(m_r[qf], mx);
                float a = exp2f(m_r[qf] - mn);
                #pragma unroll
                for (int ch = 0; ch < 4; ch++)
                    #pragma unroll
                    for (int r = 0; r < 4; r++) o[qf][ch][r] *= a;
                l_r[qf] *= a;
                m_r[qf] = mn;
            }
            float pv[8], rs = 0.f;
            #pragma unroll
            for (int i = 0; i < 8; i++) { pv[i] = exp2f(sv[i] - m_r[qf]); rs += pv[i]; }
            rs += __shfl_xor(rs, 16);
            rs += __shfl_xor(rs, 32);
            l_r[qf] += rs;

            bf16x4 w0, w1;
            #pragma unroll
            for (int r = 0; r < 4; r++) { w0[r] = f2bs(pv[r]); w1[r] = f2bs(pv[4 + r]); }
            *(bf16x4*)&P[qf * 640 + cc * 40 + g * 4]      = w0;
            *(bf16x4*)&P[qf * 640 + cc * 40 + 16 + g * 4] = w1;
        }
        asm volatile("s_waitcnt lgkmcnt(0)" ::: "memory");
        bf16x8 pa0 = *(const bf16x8*)&P[cc * 40 + g * 8];
        bf16x8 pa1 = *(const bf16x8*)&P[640 + cc * 40 + g * 8];

        #pragma unroll
        for (int ch = 0; ch < 4; ch++) {
            o[0][ch] = __builtin_amdgcn_mfma_f32_16x16x32_bf16(vf[ch], pa0, o[0][ch], 0, 0, 0);
            o[1][ch] = __builtin_amdgcn_mfma_f32_16x16x32_bf16(vf[ch], pa1, o[1][ch], 0, 0, 0);
        }
        #pragma unroll
        for (int i = 0; i < 4; i++) { kf[i] = kn[i]; vf[i] = vn[i]; }
    }

    #pragma unroll
    for (int qf = 0; qf < 2; qf++) {
        float rl = 1.0f / l_r[qf];
        const int t = q0 + qf * 16 + cc;
        #pragma unroll
        for (int ch = 0; ch < 4; ch++) {
            bf16x4 ov;
            #pragma unroll
            for (int r = 0; r < 4; r++) ov[r] = f2bs(o[qf][ch][r] * rl);
            *(bf16x4*)(Aout + ((size_t)b * 2048 + t) * 1024 + h * 64 + ch * 16 + g * 4) = ov;
        }
    }
}

// ---------------------------------------------------------------------------
// Kernel 3: projection. A bf16 [4096][1024] x Wt bf16 [1024][1024] -> f32 +bias
// ---------------------------------------------------------------------------
__global__ __launch_bounds__(256) void proj_gemm(
    const short* __restrict__ A, const short* __restrict__ Wt,
    const float* __restrict__ bias, float* __restrict__ Out)
{
    __shared__ short Al[128 * 64];
    __shared__ short Bl[128 * 64];
    const int tid  = threadIdx.x;
    const int lane = tid & 63;
    const int wid  = tid >> 6;
    const int wm = wid >> 1, wn = wid & 1;
    const int g = lane >> 4, cc = lane & 15;
    const int m0 = blockIdx.y * 128, n0 = blockIdx.x * 128;

    f32x4 acc[4][4];
    const f32x4 z4 = {0.f, 0.f, 0.f, 0.f};
    #pragma unroll
    for (int i = 0; i < 4; i++)
        #pragma unroll
        for (int j = 0; j < 4; j++) acc[i][j] = z4;

    for (int k0 = 0; k0 < 1024; k0 += 64) {
        #pragma unroll
        for (int i = 0; i < 4; i++) {
            int chunk = (wid * 4 + i) * 64 + lane;
            int row = chunk >> 3, c = chunk & 7;
            GLOAD_LDS16(A + (size_t)(m0 + row) * 1024 + k0 + c * 8, &Al[chunk * 8]);
        }
        #pragma unroll
        for (int i = 0; i < 4; i++) {
            int chunk = (wid * 4 + i) * 64 + lane;
            int row = chunk >> 3, c = chunk & 7;
            GLOAD_LDS16(Wt + (size_t)(n0 + row) * 1024 + k0 + c * 8, &Bl[chunk * 8]);
        }
        __syncthreads();

        #pragma unroll
        for (int kk = 0; kk < 2; kk++) {
            bf16x8 af[4], bfv[4];
            #pragma unroll
            for (int m = 0; m < 4; m++)
                af[m] = *(const bf16x8*)&Al[(wm * 64 + m * 16 + cc) * 64 + kk * 32 + g * 8];
            #pragma unroll
            for (int n = 0; n < 4; n++)
                bfv[n] = *(const bf16x8*)&Bl[(wn * 64 + n * 16 + cc) * 64 + kk * 32 + g * 8];
            #pragma unroll
            for (int m = 0; m < 4; m++)
                #pragma unroll
                for (int n = 0; n < 4; n++)
                    acc[m][n] = __builtin_amdgcn_mfma_f32_16x16x32_bf16(af[m], bfv[n], acc[m][n], 0, 0, 0);
        }
        __syncthreads();
    }

    #pragma unroll
    for (int n = 0; n < 4; n++) {
        int col = n0 + wn * 64 + n * 16 + cc;
        float bv = bias[col];
        #pragma unroll
        for (int m = 0; m < 4; m++) {
            #pragma unroll
            for (int r = 0; r < 4; r++) {
                int row = m0 + wm * 64 + m * 16 + g * 4 + r;
                Out[(size_t)row * 1024 + col] = acc[m][n][r] + bv;
            }
        }
    }
}

// ---------------------------------------------------------------------------
extern "C" void kernel_launch(void* const* d_in, const int* in_sizes, int n_in,
                              void* d_out, int out_size, void* d_ws, size_t ws_size,
                              hipStream_t stream)
{
    const float* x      = (const float*)d_in[0];
    const float* W_attn = (const float*)d_in[1];
    const float* b_attn = (const float*)d_in[2];
    const float* W_proj = (const float*)d_in[3];
    const float* b_proj = (const float*)d_in[4];
    float* out = (float*)d_out;

    const size_t SZ = (size_t)4096 * 1024;
    short* R1 = (short*)d_ws;                  // Wt_attn, later Aout
    short* Qw = R1 + SZ;                       // later Wt_proj
    short* Kw = Qw + SZ;
    short* Vt = Kw + SZ;

    short* Wt_attn = R1;
    short* Aout    = R1;
    short* Wt_proj = Qw;

    convt<<<dim3(48, 16), 256, 0, stream>>>(W_attn, Wt_attn, 1024, 3072);
    qkv_gemm<<<dim3(24, 32), 256, 0, stream>>>(x, Wt_attn, b_attn, Qw, Kw, Vt);
    attn_v4<<<dim3(2048), 64, 0, stream>>>(Qw, Kw, Vt, Aout);
    convt<<<dim3(16, 16), 256, 0, stream>>>(W_proj, Wt_proj, 1024, 1024);
    proj_gemm<<<dim3(8, 32), 256, 0, stream>>>(Aout, Wt_proj, b_proj, out);
}

// Round 4
// 178.537 us; speedup vs baseline: 2.5552x; 1.1759x over previous
//
#include <hip/hip_runtime.h>
#include <hip/hip_bf16.h>

// B=2, T=2048, C=1024, H=16, D=64
// convx(X) -> convt(W_attn) -> qkv_gemm -> attn_v4 -> convt(W_proj) -> proj_gemm

typedef __attribute__((ext_vector_type(8))) short bf16x8;
typedef __attribute__((ext_vector_type(4))) short bf16x4;
typedef __attribute__((ext_vector_type(4))) float f32x4;

__device__ __forceinline__ short f2bs(float f) {
    union { __hip_bfloat16 h; short s; } u;
    u.h = __float2bfloat16(f);
    return u.s;
}

#define GLOAD_LDS16(gp, lp)                                                        \
    __builtin_amdgcn_global_load_lds((const __attribute__((address_space(1))) void*)(gp), \
                                     (__attribute__((address_space(3))) void*)(lp), 16, 0, 0)

// ---------------------------------------------------------------------------
// convx: X f32 [4096*1024] -> bf16 (no transpose).  8 elems/thread.
// ---------------------------------------------------------------------------
__global__ __launch_bounds__(256) void convx(
    const float* __restrict__ X, short* __restrict__ Xb)
{
    const size_t i = ((size_t)blockIdx.x * 256 + threadIdx.x) * 8;
    float4 a = *(const float4*)(X + i);
    float4 b = *(const float4*)(X + i + 4);
    bf16x8 s;
    s[0] = f2bs(a.x); s[1] = f2bs(a.y); s[2] = f2bs(a.z); s[3] = f2bs(a.w);
    s[4] = f2bs(b.x); s[5] = f2bs(b.y); s[6] = f2bs(b.z); s[7] = f2bs(b.w);
    *(bf16x8*)(Xb + i) = s;
}

// ---------------------------------------------------------------------------
// convert + transpose: W f32 [K][N] -> Wt bf16 [N][K].  64x64 tiles via LDS.
// ---------------------------------------------------------------------------
__global__ __launch_bounds__(256) void convt(
    const float* __restrict__ W, short* __restrict__ Wt, int K, int N)
{
    __shared__ short t[64 * 72];
    const int tid = threadIdx.x;
    const int n0 = blockIdx.x * 64, k0 = blockIdx.y * 64;
    #pragma unroll
    for (int i = 0; i < 4; i++) {
        int k = (tid >> 4) + i * 16;
        int n = (tid & 15) * 4;
        float4 v = *(const float4*)(W + (size_t)(k0 + k) * N + n0 + n);
        t[(n + 0) * 72 + k] = f2bs(v.x);
        t[(n + 1) * 72 + k] = f2bs(v.y);
        t[(n + 2) * 72 + k] = f2bs(v.z);
        t[(n + 3) * 72 + k] = f2bs(v.w);
    }
    __syncthreads();
    #pragma unroll
    for (int i = 0; i < 2; i++) {
        int n  = (tid >> 3) + i * 32;
        int kc = (tid & 7) * 8;
        bf16x8 v = *(const bf16x8*)&t[n * 72 + kc];
        *(bf16x8*)(Wt + (size_t)(n0 + n) * K + k0 + kc) = v;
    }
}

// ---------------------------------------------------------------------------
// Kernel 1: QKV GEMM.  Xb bf16 [4096][1024] x Wt bf16 [3072][1024] (+bias)
// 128x128 tile, BK=64, 4 waves, both operands via global_load_lds (m97).
// Q output pre-scaled by log2(e)/sqrt(C).
// ---------------------------------------------------------------------------
__global__ __launch_bounds__(256) void qkv_gemm(
    const short* __restrict__ Xb, const short* __restrict__ Wt,
    const float* __restrict__ bias,
    short* __restrict__ Qw, short* __restrict__ Kw, short* __restrict__ Vt)
{
    __shared__ short Al[128 * 64];
    __shared__ short Bl[128 * 64];
    const int tid  = threadIdx.x;
    const int lane = tid & 63;
    const int wid  = tid >> 6;
    const int wm = wid >> 1, wn = wid & 1;
    const int g = lane >> 4, cc = lane & 15;
    const int m0 = blockIdx.y * 128, n0 = blockIdx.x * 128;

    f32x4 acc[4][4];
    const f32x4 z4 = {0.f, 0.f, 0.f, 0.f};
    #pragma unroll
    for (int i = 0; i < 4; i++)
        #pragma unroll
        for (int j = 0; j < 4; j++) acc[i][j] = z4;

    for (int k0 = 0; k0 < 1024; k0 += 64) {
        #pragma unroll
        for (int i = 0; i < 4; i++) {
            int chunk = (wid * 4 + i) * 64 + lane;
            int row = chunk >> 3, c = chunk & 7;
            GLOAD_LDS16(Xb + (size_t)(m0 + row) * 1024 + k0 + c * 8, &Al[chunk * 8]);
        }
        #pragma unroll
        for (int i = 0; i < 4; i++) {
            int chunk = (wid * 4 + i) * 64 + lane;
            int row = chunk >> 3, c = chunk & 7;
            GLOAD_LDS16(Wt + (size_t)(n0 + row) * 1024 + k0 + c * 8, &Bl[chunk * 8]);
        }
        __syncthreads();

        #pragma unroll
        for (int kk = 0; kk < 2; kk++) {
            bf16x8 af[4], bfv[4];
            #pragma unroll
            for (int m = 0; m < 4; m++)
                af[m] = *(const bf16x8*)&Al[(wm * 64 + m * 16 + cc) * 64 + kk * 32 + g * 8];
            #pragma unroll
            for (int n = 0; n < 4; n++)
                bfv[n] = *(const bf16x8*)&Bl[(wn * 64 + n * 16 + cc) * 64 + kk * 32 + g * 8];
            #pragma unroll
            for (int m = 0; m < 4; m++)
                #pragma unroll
                for (int n = 0; n < 4; n++)
                    acc[m][n] = __builtin_amdgcn_mfma_f32_16x16x32_bf16(af[m], bfv[n], acc[m][n], 0, 0, 0);
        }
        __syncthreads();
    }

    const float QSCALE = 0.04508422976f;   // log2(e)/sqrt(1024)
    #pragma unroll
    for (int n = 0; n < 4; n++) {
        int col = n0 + wn * 64 + n * 16 + cc;
        int which = col >> 10;
        int ci = col & 1023;
        int h = ci >> 6, d = ci & 63;
        float bv = bias[col];
        #pragma unroll
        for (int m = 0; m < 4; m++) {
            #pragma unroll
            for (int r = 0; r < 4; r++) {
                int row = m0 + wm * 64 + m * 16 + g * 4 + r;
                int b = row >> 11, t = row & 2047;
                int bh = b * 16 + h;
                float v = acc[m][n][r] + bv;
                if (which == 0)      Qw[((size_t)bh * 2048 + t) * 64 + d] = f2bs(v * QSCALE);
                else if (which == 1) Kw[((size_t)bh * 2048 + t) * 64 + d] = f2bs(v);
                else                 Vt[((size_t)bh * 64 + d) * 2048 + t] = f2bs(v);
            }
        }
    }
}

// ---------------------------------------------------------------------------
// Kernel 2: causal flash attention, swapped S^T form, 32 q-rows per wave.
// ---------------------------------------------------------------------------
__global__ __launch_bounds__(64) void attn_v4(
    const short* __restrict__ Qw, const short* __restrict__ Kw,
    const short* __restrict__ Vt, short* __restrict__ Aout)
{
    __shared__ short P[2 * 16 * 40];
    const int lane = threadIdx.x;
    const int g = lane >> 4, cc = lane & 15;
    const int bid = blockIdx.x;
    const int qt = 63 - (bid >> 5);       // longest tiles first
    const int bh = bid & 31;              // XCD = bh % 8 -> per-head L2 locality
    const int q0 = qt * 32;
    const int b = bh >> 4, h = bh & 15;
    const short* Qb = Qw + (size_t)bh * 2048 * 64;
    const short* Kb = Kw + (size_t)bh * 2048 * 64;
    const short* Vb = Vt + (size_t)bh * 64 * 2048;

    bf16x8 qfr[2][2];
    #pragma unroll
    for (int qf = 0; qf < 2; qf++)
        #pragma unroll
        for (int ds = 0; ds < 2; ds++)
            qfr[qf][ds] = *(const bf16x8*)(Qb + (q0 + qf * 16 + cc) * 64 + ds * 32 + g * 8);

    const f32x4 z4 = {0.f, 0.f, 0.f, 0.f};
    f32x4 o[2][4];
    #pragma unroll
    for (int qf = 0; qf < 2; qf++)
        #pragma unroll
        for (int ch = 0; ch < 4; ch++) o[qf][ch] = z4;
    float m_r[2] = {-1e30f, -1e30f}, l_r[2] = {0.f, 0.f};

    const int nsteps = qt + 1;

    bf16x8 kf[4], vf[4];
    #pragma unroll
    for (int kvc = 0; kvc < 2; kvc++)
        #pragma unroll
        for (int ds = 0; ds < 2; ds++)
            kf[kvc * 2 + ds] = *(const bf16x8*)(Kb + (kvc * 16 + cc) * 64 + ds * 32 + g * 8);
    #pragma unroll
    for (int ch = 0; ch < 4; ch++)
        vf[ch] = *(const bf16x8*)(Vb + (ch * 16 + cc) * 2048 + g * 8);

    for (int st = 0; st < nsteps; st++) {
        const int kv0 = st * 32;
        const int kvn = (st + 1 < nsteps) ? kv0 + 32 : kv0;
        bf16x8 kn[4], vn[4];
        #pragma unroll
        for (int kvc = 0; kvc < 2; kvc++)
            #pragma unroll
            for (int ds = 0; ds < 2; ds++)
                kn[kvc * 2 + ds] = *(const bf16x8*)(Kb + (kvn + kvc * 16 + cc) * 64 + ds * 32 + g * 8);
        #pragma unroll
        for (int ch = 0; ch < 4; ch++)
            vn[ch] = *(const bf16x8*)(Vb + (ch * 16 + cc) * 2048 + kvn + g * 8);

        f32x4 s[2][2];
        #pragma unroll
        for (int qf = 0; qf < 2; qf++)
            #pragma unroll
            for (int kvc = 0; kvc < 2; kvc++) {
                s[qf][kvc] = z4;
                #pragma unroll
                for (int ds = 0; ds < 2; ds++)
                    s[qf][kvc] = __builtin_amdgcn_mfma_f32_16x16x32_bf16(
                        kf[kvc * 2 + ds], qfr[qf][ds], s[qf][kvc], 0, 0, 0);
            }

        const bool masked = (st == qt);
        #pragma unroll
        for (int qf = 0; qf < 2; qf++) {
            const int qq = q0 + qf * 16 + cc;
            float sv[8];
            #pragma unroll
            for (int kvc = 0; kvc < 2; kvc++)
                #pragma unroll
                for (int r = 0; r < 4; r++) {
                    float v = s[qf][kvc][r];
                    if (masked) {
                        int kv = kv0 + kvc * 16 + g * 4 + r;
                        v = (kv <= qq) ? v : -1e30f;
                    }
                    sv[kvc * 4 + r] = v;
                }
            float mx = fmaxf(fmaxf(fmaxf(sv[0], sv[1]), fmaxf(sv[2], sv[3])),
                             fmaxf(fmaxf(sv[4], sv[5]), fmaxf(sv[6], sv[7])));
            mx = fmaxf(mx, __shfl_xor(mx, 16));
            mx = fmaxf(mx, __shfl_xor(mx, 32));
            if (__any(mx > m_r[qf] + 6.0f)) {
                float mn = fmaxf(m_r[qf], mx);
                float a = exp2f(m_r[qf] - mn);
                #pragma unroll
                for (int ch = 0; ch < 4; ch++)
                    #pragma unroll
                    for (int r = 0; r < 4; r++) o[qf][ch][r] *= a;
                l_r[qf] *= a;
                m_r[qf] = mn;
            }
            float pv[8], rs = 0.f;
            #pragma unroll
            for (int i = 0; i < 8; i++) { pv[i] = exp2f(sv[i] - m_r[qf]); rs += pv[i]; }
            rs += __shfl_xor(rs, 16);
            rs += __shfl_xor(rs, 32);
            l_r[qf] += rs;

            bf16x4 w0, w1;
            #pragma unroll
            for (int r = 0; r < 4; r++) { w0[r] = f2bs(pv[r]); w1[r] = f2bs(pv[4 + r]); }
            *(bf16x4*)&P[qf * 640 + cc * 40 + g * 4]      = w0;
            *(bf16x4*)&P[qf * 640 + cc * 40 + 16 + g * 4] = w1;
        }
        asm volatile("s_waitcnt lgkmcnt(0)" ::: "memory");
        bf16x8 pa0 = *(const bf16x8*)&P[cc * 40 + g * 8];
        bf16x8 pa1 = *(const bf16x8*)&P[640 + cc * 40 + g * 8];

        #pragma unroll
        for (int ch = 0; ch < 4; ch++) {
            o[0][ch] = __builtin_amdgcn_mfma_f32_16x16x32_bf16(vf[ch], pa0, o[0][ch], 0, 0, 0);
            o[1][ch] = __builtin_amdgcn_mfma_f32_16x16x32_bf16(vf[ch], pa1, o[1][ch], 0, 0, 0);
        }
        #pragma unroll
        for (int i = 0; i < 4; i++) { kf[i] = kn[i]; vf[i] = vn[i]; }
    }

    #pragma unroll
    for (int qf = 0; qf < 2; qf++) {
        float rl = 1.0f / l_r[qf];
        const int t = q0 + qf * 16 + cc;
        #pragma unroll
        for (int ch = 0; ch < 4; ch++) {
            bf16x4 ov;
            #pragma unroll
            for (int r = 0; r < 4; r++) ov[r] = f2bs(o[qf][ch][r] * rl);
            *(bf16x4*)(Aout + ((size_t)b * 2048 + t) * 1024 + h * 64 + ch * 16 + g * 4) = ov;
        }
    }
}

// ---------------------------------------------------------------------------
// Kernel 3: projection. A bf16 [4096][1024] x Wt bf16 [1024][1024] -> f32 +bias
// 128x64 tile (512 blocks = 2/CU), BK=64, 4 waves (2x2), each wave 64x32.
// ---------------------------------------------------------------------------
__global__ __launch_bounds__(256) void proj_gemm(
    const short* __restrict__ A, const short* __restrict__ Wt,
    const float* __restrict__ bias, float* __restrict__ Out)
{
    __shared__ short Al[128 * 64];
    __shared__ short Bl[64 * 64];
    const int tid  = threadIdx.x;
    const int lane = tid & 63;
    const int wid  = tid >> 6;
    const int wm = wid >> 1, wn = wid & 1;
    const int g = lane >> 4, cc = lane & 15;
    const int m0 = blockIdx.y * 128, n0 = blockIdx.x * 64;

    f32x4 acc[4][2];
    const f32x4 z4 = {0.f, 0.f, 0.f, 0.f};
    #pragma unroll
    for (int i = 0; i < 4; i++)
        #pragma unroll
        for (int j = 0; j < 2; j++) acc[i][j] = z4;

    for (int k0 = 0; k0 < 1024; k0 += 64) {
        #pragma unroll
        for (int i = 0; i < 4; i++) {
            int chunk = (wid * 4 + i) * 64 + lane;
            int row = chunk >> 3, c = chunk & 7;
            GLOAD_LDS16(A + (size_t)(m0 + row) * 1024 + k0 + c * 8, &Al[chunk * 8]);
        }
        #pragma unroll
        for (int i = 0; i < 2; i++) {
            int chunk = (wid * 2 + i) * 64 + lane;
            int row = chunk >> 3, c = chunk & 7;
            GLOAD_LDS16(Wt + (size_t)(n0 + row) * 1024 + k0 + c * 8, &Bl[chunk * 8]);
        }
        __syncthreads();

        #pragma unroll
        for (int kk = 0; kk < 2; kk++) {
            bf16x8 af[4], bfv[2];
            #pragma unroll
            for (int m = 0; m < 4; m++)
                af[m] = *(const bf16x8*)&Al[(wm * 64 + m * 16 + cc) * 64 + kk * 32 + g * 8];
            #pragma unroll
            for (int n = 0; n < 2; n++)
                bfv[n] = *(const bf16x8*)&Bl[(wn * 32 + n * 16 + cc) * 64 + kk * 32 + g * 8];
            #pragma unroll
            for (int m = 0; m < 4; m++)
                #pragma unroll
                for (int n = 0; n < 2; n++)
                    acc[m][n] = __builtin_amdgcn_mfma_f32_16x16x32_bf16(af[m], bfv[n], acc[m][n], 0, 0, 0);
        }
        __syncthreads();
    }

    #pragma unroll
    for (int n = 0; n < 2; n++) {
        int col = n0 + wn * 32 + n * 16 + cc;
        float bv = bias[col];
        #pragma unroll
        for (int m = 0; m < 4; m++) {
            #pragma unroll
            for (int r = 0; r < 4; r++) {
                int row = m0 + wm * 64 + m * 16 + g * 4 + r;
                Out[(size_t)row * 1024 + col] = acc[m][n][r] + bv;
            }
        }
    }
}

// ---------------------------------------------------------------------------
extern "C" void kernel_launch(void* const* d_in, const int* in_sizes, int n_in,
                              void* d_out, int out_size, void* d_ws, size_t ws_size,
                              hipStream_t stream)
{
    const float* x      = (const float*)d_in[0];
    const float* W_attn = (const float*)d_in[1];
    const float* b_attn = (const float*)d_in[2];
    const float* W_proj = (const float*)d_in[3];
    const float* b_proj = (const float*)d_in[4];
    float* out = (float*)d_out;

    const size_t SZ = (size_t)4096 * 1024;
    short* R1 = (short*)d_ws;                  // Wt_attn, later Aout
    short* Qw = R1 + SZ;                       // later Wt_proj
    short* Kw = Qw + SZ;
    short* Vt = Kw + SZ;

    short* Wt_attn = R1;
    short* Aout    = R1;
    short* Wt_proj = Qw;
    short* Xb      = (short*)d_out;            // d_out as bf16 scratch until proj

    convx<<<dim3(2048), 256, 0, stream>>>(x, Xb);
    convt<<<dim3(48, 16), 256, 0, stream>>>(W_attn, Wt_attn, 1024, 3072);
    qkv_gemm<<<dim3(24, 32), 256, 0, stream>>>(Xb, Wt_attn, b_attn, Qw, Kw, Vt);
    attn_v4<<<dim3(2048), 64, 0, stream>>>(Qw, Kw, Vt, Aout);
    convt<<<dim3(16, 16), 256, 0, stream>>>(W_proj, Wt_proj, 1024, 1024);
    proj_gemm<<<dim3(16, 32), 256, 0, stream>>>(Aout, Wt_proj, b_proj, out);
}